// Round 1
// baseline (618.474 us; speedup 1.0000x reference)
//
#include <hip/hip_runtime.h>
#include <hip/hip_bf16.h>

// Problem constants (from reference setup_inputs)
constexpr int NN   = 50000;   // nodes
constexpr int EE   = 400000;  // edges (before self loops)
constexpr int EP   = 450000;  // edges + self loops
constexpr int D    = 512;     // HEADS*CH
constexpr int D2   = 1024;    // XL||XR fused row stride
constexpr int F0   = 55;      // input feature dim
constexpr int F0P  = 64;      // padded to MFMA K granularity
constexpr int OUTC = 49;      // classifier out dim

typedef __hip_bfloat16 bf16;

using frag_ab  = __attribute__((ext_vector_type(8))) short;   // 8 bf16 (4 VGPRs)
using frag_cd16 = __attribute__((ext_vector_type(16))) float; // 16 fp32 (32x32 acc)

__device__ inline void stf(float* p, float v) { *p = v; }
__device__ inline void stf(bf16* p, float v)  { *p = __float2bfloat16(v); }

// unpack 8 bf16 (packed in a uint4) to 8 floats
__device__ inline void unpack8(uint4 u, float* f) {
    unsigned w[4] = {u.x, u.y, u.z, u.w};
    #pragma unroll
    for (int j = 0; j < 4; ++j) {
        __hip_bfloat162 h = *(__hip_bfloat162*)&w[j];
        float2 t = __bfloat1622float2(h);
        f[2 * j] = t.x; f[2 * j + 1] = t.y;
    }
}

// ---------------------------------------------------------------------------
// MFMA bf16 GEMM: C[M,*] = A @ B, B TRANSPOSED as Bt[*,K].
// Round-11: depth-2 software pipeline (T3+T4 counted-vmcnt recipe).
// Previous structure drained vmcnt(0) + __syncthreads every BK=32 step ->
// ~1265 cyc exposed latency/step vs ~256 cyc MFMA demand (MfmaUtil 21.6%,
// 509 TF; both HBM (17%) and MFMA pipes far from their rooflines => pure
// latency bind). Now: 3 LDS slots (48 KB, 3 blocks/CU = same effective
// residency as measured 27% occupancy), stage(t+2) issued each iter, RAW
// protected by counted `s_waitcnt vmcnt(4)` + raw s_barrier (loads from two
// steps ahead stay in flight across the barrier; never drain to 0 in the
// main loop). WAR on the 3-deep ring is protected by the single front
// barrier (stage(t+2) overwrites the slot last read at compute(t-1), which
// is program-ordered before this barrier in every wave).
// 128x128 tile, BK=32, 256 thr, 2x2 frags of v_mfma_f32_32x32x16_bf16.
// gridDim.x==8 -> XCD swizzle (A slab L2-resident; FETCH 202->35 MB
// verified round 7). Do NOT re-attempt LDS swizzle/BK=64 (r8 regression:
// conflicts were 0.03% of cycles; occupancy loss dominated).
// ---------------------------------------------------------------------------
template <typename TC>
__global__ __launch_bounds__(256) void gemm_mfma_bt(
    const bf16* __restrict__ A,   // [M,K]
    const bf16* __restrict__ Bt,  // [gridx*128, K]
    TC* __restrict__ C,           // [M, Ncs]
    const float* __restrict__ bias,
    int M, int Ncs, int K)
{
    constexpr int BM = 128, BN = 128, BK = 32;
    __shared__ __align__(16) bf16 As[3][BM * BK];  // 3-deep ring, 8 KB/slot
    __shared__ __align__(16) bf16 Bs[3][BN * BK];

    int bx = blockIdx.x, by = blockIdx.y;
    if (gridDim.x == 8) {
        int bid = by * 8 + bx;
        bx = (bid >> 3) & 7;
        by = (bid & 7) + ((bid >> 6) << 3);
        if (by * BM >= M) return;   // uniform across block
    }

    const int tid  = threadIdx.x;
    const int wave = tid >> 6;
    const int lane = tid & 63;
    const int rowBase = by * BM;
    const int colBase = bx * BN;

    frag_cd16 acc[2][2] = {};

    int arow0 = rowBase + wave * 32 + (lane >> 2);
    int arow1 = arow0 + 16;
    if (arow0 >= M) arow0 = M - 1;   // clamp: garbage rows never stored
    if (arow1 >= M) arow1 = M - 1;
    const bf16* gA0 = A + (size_t)arow0 * K + (lane & 3) * 8;
    const bf16* gA1 = A + (size_t)arow1 * K + (lane & 3) * 8;
    const int brow0 = colBase + wave * 32 + (lane >> 2);
    const bf16* gB0 = Bt + (size_t)brow0 * K + (lane & 3) * 8;
    const bf16* gB1 = gB0 + (size_t)16 * K;

    const int aoff0 = (wave * 32)      * BK;   // element offsets within a slot
    const int aoff1 = (wave * 32 + 16) * BK;

    const int m32 = lane & 31;      // row (A) / col (B) within 32
    const int kh  = lane >> 5;      // k-half: k offset = kh*8
    const int wm = (wave >> 1) * 64;
    const int wn = (wave & 1) * 64;

    // issue the 4 staging loads for K-step t into ring slot t%3
    auto stage = [&](int t) {
        const int slot = t % 3;
        const int kc = t * BK;
        __builtin_amdgcn_global_load_lds(
            (const __attribute__((address_space(1))) void*)(gA0 + kc),
            (__attribute__((address_space(3))) void*)(As[slot] + aoff0), 16, 0, 0);
        __builtin_amdgcn_global_load_lds(
            (const __attribute__((address_space(1))) void*)(gA1 + kc),
            (__attribute__((address_space(3))) void*)(As[slot] + aoff1), 16, 0, 0);
        __builtin_amdgcn_global_load_lds(
            (const __attribute__((address_space(1))) void*)(gB0 + kc),
            (__attribute__((address_space(3))) void*)(Bs[slot] + aoff0), 16, 0, 0);
        __builtin_amdgcn_global_load_lds(
            (const __attribute__((address_space(1))) void*)(gB1 + kc),
            (__attribute__((address_space(3))) void*)(Bs[slot] + aoff1), 16, 0, 0);
    };

    // consume ring slot: 8 ds_read_b128 + 8 MFMA (compiler manages lgkmcnt)
    auto compute = [&](int slot) {
        const bf16* Ab = As[slot];
        const bf16* Bb = Bs[slot];
        #pragma unroll
        for (int kk = 0; kk < 2; ++kk) {     // two K=16 steps per BK=32
            const int koff = kk * 16 + kh * 8;
            frag_ab a[2], b[2];
            #pragma unroll
            for (int i = 0; i < 2; ++i)
                a[i] = *(const frag_ab*)&Ab[(wm + i * 32 + m32) * BK + koff];
            #pragma unroll
            for (int j = 0; j < 2; ++j)
                b[j] = *(const frag_ab*)&Bb[(wn + j * 32 + m32) * BK + koff];
            #pragma unroll
            for (int i = 0; i < 2; ++i)
                #pragma unroll
                for (int j = 0; j < 2; ++j)
                    acc[i][j] = __builtin_amdgcn_mfma_f32_32x32x16_bf16(
                        a[i], b[j], acc[i][j], 0, 0, 0);
        }
    };

    const int nt = K / BK;          // >= 2 for every call site (K=64..512)
    stage(0);
    stage(1);

    // main loop: counted vmcnt keeps 4-8 loads in flight ACROSS the barrier.
    // vmcnt(4): of the (up to) 8 outstanding staging loads, the oldest 4
    // (step t's) have landed in LDS; step t+1's stay in flight. Safe against
    // any extra compiler-scheduled VMEM (only lengthens the wait).
    for (int t = 0; t < nt - 2; ++t) {
        asm volatile("s_waitcnt vmcnt(4)" ::: "memory");
        __builtin_amdgcn_s_barrier();
        asm volatile("" ::: "memory");
        stage(t + 2);
        asm volatile("" ::: "memory");
        compute(t % 3);
    }
    // tail: steps nt-2 and nt-1 (no further staging)
    asm volatile("s_waitcnt vmcnt(4)" ::: "memory");
    __builtin_amdgcn_s_barrier();
    asm volatile("" ::: "memory");
    compute((nt - 2) % 3);
    asm volatile("s_waitcnt vmcnt(0)" ::: "memory");
    __builtin_amdgcn_s_barrier();
    asm volatile("" ::: "memory");
    compute((nt - 1) % 3);

    // epilogue: 32x32 C/D layout col=lane&31, row=(reg&3)+8*(reg>>2)+4*(lane>>5)
    // [m74/m101 verified; dtype-independent]
    #pragma unroll
    for (int i = 0; i < 2; ++i) {
        #pragma unroll
        for (int r = 0; r < 16; ++r) {
            int row = rowBase + wm + i * 32 + (r & 3) + 8 * (r >> 2) + 4 * kh;
            if (row >= M) continue;
            #pragma unroll
            for (int j = 0; j < 2; ++j) {
                int col = colBase + wn + j * 32 + m32;
                if (col >= Ncs) continue;
                float v = acc[i][j][r];
                if (bias) v += bias[col];
                stf(&C[(size_t)row * Ncs + col], v);
            }
        }
    }
}

// ---------------------------------------------------------------------------
// weight prep kernels
// ---------------------------------------------------------------------------
// fp32 W[512,512] x2 -> bf16 Wt[1024,512] (transposed, stacked), grid.z=2
__global__ void convert_transpose2(const float* __restrict__ W0,
                                   const float* __restrict__ W1,
                                   bf16* __restrict__ Wt) {
    __shared__ float tile[32][33];
    const float* W = blockIdx.z ? W1 : W0;
    bf16* dst = Wt + (size_t)blockIdx.z * D * D;
    int bn = blockIdx.x * 32, bk = blockIdx.y * 32;
    int tx = threadIdx.x & 31, ty = threadIdx.x >> 5;  // 32x8
    #pragma unroll
    for (int i = 0; i < 32; i += 8)
        tile[ty + i][tx] = W[(size_t)(bk + ty + i) * D + bn + tx];
    __syncthreads();
    #pragma unroll
    for (int i = 0; i < 32; i += 8)
        dst[(size_t)(bn + ty + i) * D + bk + tx] = __float2bfloat16(tile[tx][ty + i]);
}

__global__ void pad_convert_x(const float* __restrict__ x, bf16* __restrict__ Xp) {
    int idx = blockIdx.x * blockDim.x + threadIdx.x;
    if (idx >= NN * F0P) return;
    int n = idx >> 6, t = idx & 63;
    float v = (t < F0) ? x[n * F0 + t] : 0.f;
    Xp[idx] = __float2bfloat16(v);
}

// W1{l,r}[55,512] fp32 -> W1T[1024,64] bf16 (zero pad K), grid.y=2
__global__ void conv_transpose_w1(const float* __restrict__ Wl,
                                  const float* __restrict__ Wr,
                                  bf16* __restrict__ Wt) {
    const float* W = blockIdx.y ? Wr : Wl;
    bf16* dst = Wt + (size_t)blockIdx.y * D * F0P;
    int n = blockIdx.x;           // 512
    int k = threadIdx.x;          // 64
    float v = (k < F0) ? W[(size_t)k * D + n] : 0.f;
    dst[n * F0P + k] = __float2bfloat16(v);
}

__global__ void conv_transpose_wc(const float* __restrict__ W, bf16* __restrict__ Wt) {
    int n = blockIdx.x;           // 128
    for (int k = threadIdx.x; k < D; k += blockDim.x) {
        float v = (n < OUTC) ? W[(size_t)k * OUTC + n] : 0.f;
        Wt[(size_t)n * D + k] = __float2bfloat16(v);
    }
}

// ---------------------------------------------------------------------------
__global__ void zero_ints(int* __restrict__ p, int n) {
    int i = blockIdx.x * blockDim.x + threadIdx.x;
    if (i < n) p[i] = 0;
}

// ---------------------------------------------------------------------------
// CSR build by destination; srcPos[pos] = source node of CSR slot pos
// ---------------------------------------------------------------------------
__global__ void count_dst(const int* __restrict__ dstIdx, int* __restrict__ cnt) {
    int e = blockIdx.x * blockDim.x + threadIdx.x;
    if (e >= EP) return;
    int dst = (e < EE) ? dstIdx[e] : (e - EE);
    atomicAdd(&cnt[dst], 1);
}

__global__ void scan_blocks(const int* __restrict__ cnt, int* __restrict__ off,
                            int* __restrict__ bsum) {
    __shared__ int sh[1024];
    int i = blockIdx.x * 1024 + threadIdx.x;
    int v = (i < NN) ? cnt[i] : 0;
    sh[threadIdx.x] = v;
    __syncthreads();
    #pragma unroll
    for (int d = 1; d < 1024; d <<= 1) {
        int t = (threadIdx.x >= d) ? sh[threadIdx.x - d] : 0;
        __syncthreads();
        sh[threadIdx.x] += t;
        __syncthreads();
    }
    if (i < NN) off[i] = sh[threadIdx.x] - v;   // local exclusive
    if (threadIdx.x == 1023) bsum[blockIdx.x] = sh[1023];
}

__global__ void scan_bsums(int* __restrict__ bsum, int* __restrict__ bbase,
                           int* __restrict__ off, int nb) {
    int lane = threadIdx.x;  // single wave of 64
    int orig = (lane < nb) ? bsum[lane] : 0;
    int v = orig;
    #pragma unroll
    for (int d = 1; d < 64; d <<= 1) {
        int t = __shfl_up(v, d);
        if (lane >= d) v += t;
    }
    if (lane < nb) bbase[lane] = v - orig;      // exclusive base per block
    if (lane == 63) off[NN] = v;                // grand total
}

__global__ void add_base(int* __restrict__ off, const int* __restrict__ bbase) {
    int i = blockIdx.x * 1024 + threadIdx.x;
    if (blockIdx.x == 0 || i >= NN) return;
    off[i] += bbase[blockIdx.x];
}

__global__ void fill_srcpos(const int* __restrict__ srcIdx, const int* __restrict__ dstIdx,
                            const int* __restrict__ off, int* __restrict__ cnt,
                            int* __restrict__ srcPos) {
    int e = blockIdx.x * blockDim.x + threadIdx.x;
    if (e >= EP) return;
    int dst = (e < EE) ? dstIdx[e] : (e - EE);
    int src = (e < EE) ? srcIdx[e] : (e - EE);
    int pos = off[dst] + atomicAdd(&cnt[dst], 1);
    srcPos[pos] = src;
}

// ---------------------------------------------------------------------------
// FUSED per-node GATv2 edge phase — round-10 exact version (measured best).
// ONE wave per destination node, depth-2 prefetch, clamped-exp softmax.
// Lane l owns channels [l*8, l*8+8); head = l>>4.
// XLR row layout: [XL(512) | XR(512)] bf16, stride D2. Output Hb + bias + ELU.
// ---------------------------------------------------------------------------
__global__ __launch_bounds__(256) void gat_edge_fused(
    const bf16* __restrict__ XLR, const float* __restrict__ att,
    const int* __restrict__ off, const int* __restrict__ srcPos,
    const float* __restrict__ bias, bf16* __restrict__ Hout)
{
    int v = blockIdx.x * 4 + (threadIdx.x >> 6);
    if (v >= NN) return;
    int lane = threadIdx.x & 63;

    uint4 ru = *(const uint4*)(XLR + (size_t)v * D2 + D + lane * 8);
    float xr[8]; unpack8(ru, xr);
    const float4* a4 = (const float4*)(att + lane * 8);
    float4 aa = a4[0], ab = a4[1];
    float at[8] = {aa.x, aa.y, aa.z, aa.w, ab.x, ab.y, ab.z, ab.w};

    int s0 = off[v], s1 = off[v + 1];
    float den = 0.f;
    float acc[8] = {};

    uint4 lb0 = {0, 0, 0, 0}, lb1 = {0, 0, 0, 0};
    if (s0 < s1)     lb0 = *(const uint4*)(XLR + (size_t)srcPos[s0] * D2 + lane * 8);
    if (s0 + 1 < s1) lb1 = *(const uint4*)(XLR + (size_t)srcPos[s0 + 1] * D2 + lane * 8);

    for (int i = s0; i < s1; ++i) {
        uint4 cur = lb0;
        lb0 = lb1;
        if (i + 2 < s1)
            lb1 = *(const uint4*)(XLR + (size_t)srcPos[i + 2] * D2 + lane * 8);

        float xl[8]; unpack8(cur, xl);
        float sa = 0.f, sb = 0.f;
        #pragma unroll
        for (int j = 0; j < 4; ++j) {
            float t = xl[j] + xr[j];
            t = fmaxf(t, 0.2f * t);          // leaky relu (valid both signs)
            sa = fmaf(t, at[j], sa);
        }
        #pragma unroll
        for (int j = 4; j < 8; ++j) {
            float t = xl[j] + xr[j];
            t = fmaxf(t, 0.2f * t);
            sb = fmaf(t, at[j], sb);
        }
        float s = sa + sb;
        s += __shfl_xor(s, 1);
        s += __shfl_xor(s, 2);
        s += __shfl_xor(s, 4);
        s += __shfl_xor(s, 8);               // 16 lanes of head hold logit
        s = fminf(fmaxf(s, -60.f), 60.f);    // shift-free softmax, clamped
        float p = __expf(s);
        den += p;
        #pragma unroll
        for (int j = 0; j < 8; ++j) acc[j] = fmaf(p, xl[j], acc[j]);
    }
    float r = 1.f / den;

    const float4* b4 = (const float4*)(bias + lane * 8);
    float4 ba = b4[0], bb = b4[1];
    float bi[8] = {ba.x, ba.y, ba.z, ba.w, bb.x, bb.y, bb.z, bb.w};
    uint4 ou;
    unsigned* ow = (unsigned*)&ou;
    #pragma unroll
    for (int j = 0; j < 4; ++j) {
        float o0 = acc[2 * j] * r + bi[2 * j];
        float o1 = acc[2 * j + 1] * r + bi[2 * j + 1];
        o0 = o0 > 0.f ? o0 : (__expf(o0) - 1.f);   // ELU
        o1 = o1 > 0.f ? o1 : (__expf(o1) - 1.f);
        __hip_bfloat162 h{__float2bfloat16(o0), __float2bfloat16(o1)};
        ow[j] = *(unsigned*)&h;
    }
    *(uint4*)(Hout + (size_t)v * D + lane * 8) = ou;
}

// ---------------------------------------------------------------------------
extern "C" void kernel_launch(void* const* d_in, const int* in_sizes, int n_in,
                              void* d_out, int out_size, void* d_ws, size_t ws_size,
                              hipStream_t stream) {
    const float* x    = (const float*)d_in[0];
    const int*   ei   = (const int*)d_in[1];
    const float* W1l  = (const float*)d_in[2];
    const float* W1r  = (const float*)d_in[3];
    const float* att1 = (const float*)d_in[4];
    const float* b1   = (const float*)d_in[5];
    const float* W2l  = (const float*)d_in[6];
    const float* W2r  = (const float*)d_in[7];
    const float* att2 = (const float*)d_in[8];
    const float* b2   = (const float*)d_in[9];
    const float* Wc   = (const float*)d_in[10];
    const float* bc   = (const float*)d_in[11];
    float* out = (float*)d_out;

    const int* srcIdx = ei;
    const int* dstIdx = ei + EE;

    constexpr int NB = (NN + 1023) / 1024;   // 49 scan blocks

    // workspace carve — total ≈ 166 MB
    bf16* XLR  = (bf16*)d_ws;                    // NN*D2   (XL || XR)
    bf16* Hb   = XLR + (size_t)NN * D2;          // NN*D
    bf16* Xpad = Hb + (size_t)NN * D;            // NN*F0P
    bf16* W2T  = Xpad + (size_t)NN * F0P;        // 1024*D   (W2lT || W2rT rows)
    bf16* W1T  = W2T + (size_t)D2 * D;           // 1024*F0P
    bf16* WcT  = W1T + (size_t)D2 * F0P;         // 128*D
    int* cnt   = (int*)(WcT + (size_t)128 * D);  // NN
    int* cnt2  = cnt + NN;                       // NN
    int* off   = cnt2 + NN;                      // NN+1
    int* srcPos= off + (NN + 1);                 // EP
    int* bsum  = srcPos + EP;                    // NB
    int* bbase = bsum + NB;                      // NB

    // ---- one-time per call: CSR build + weight prep ----
    zero_ints<<<(2 * NN + 255) / 256, 256, 0, stream>>>(cnt, 2 * NN);
    count_dst<<<(EP + 255) / 256, 256, 0, stream>>>(dstIdx, cnt);
    scan_blocks<<<NB, 1024, 0, stream>>>(cnt, off, bsum);
    scan_bsums<<<1, 64, 0, stream>>>(bsum, bbase, off, NB);
    add_base<<<NB, 1024, 0, stream>>>(off, bbase);
    fill_srcpos<<<(EP + 255) / 256, 256, 0, stream>>>(srcIdx, dstIdx, off, cnt2, srcPos);

    dim3 ctGrid(D / 32, D / 32, 2);
    convert_transpose2<<<ctGrid, 256, 0, stream>>>(W2l, W2r, W2T);
    dim3 w1Grid(D, 2);
    conv_transpose_w1<<<w1Grid, F0P, 0, stream>>>(W1l, W1r, W1T);
    conv_transpose_wc<<<128, 256, 0, stream>>>(Wc, WcT);
    pad_convert_x<<<(NN * F0P + 255) / 256, 256, 0, stream>>>(x, Xpad);

    // fused L+R GEMM: N=1024, grid.y padded so the XCD swizzle covers all slabs
    dim3 gemmGrid(D2 / 128, ((NN + 127) / 128 + 7) / 8 * 8 + 8);  // 8 x 400
    int nodeBlocks = (NN + 3) / 4;

    // ---- layer 1 (Xpad bf16, K=64): one GEMM produces XL||XR ----
    gemm_mfma_bt<bf16><<<gemmGrid, 256, 0, stream>>>(Xpad, W1T, XLR, nullptr, NN, D2, F0P);
    gat_edge_fused<<<nodeBlocks, 256, 0, stream>>>(XLR, att1, off, srcPos, b1, Hb);

    // ---- layers 2 & 3 (bf16 Hb, K=512; conv2 applied twice) ----
    for (int rep = 0; rep < 2; ++rep) {
        gemm_mfma_bt<bf16><<<gemmGrid, 256, 0, stream>>>(Hb, W2T, XLR, nullptr, NN, D2, D);
        gat_edge_fused<<<nodeBlocks, 256, 0, stream>>>(XLR, att2, off, srcPos, b2, Hb);
    }

    // ---- classifier: C[NN,49] fp32 = Hb @ Wc + bc (N padded to 128) ----
    dim3 gridc(1, (NN + 127) / 128);
    gemm_mfma_bt<float><<<gridc, 256, 0, stream>>>(Hb, WcT, out, bc, NN, OUTC, D);
}

// Round 2
// 606.320 us; speedup vs baseline: 1.0200x; 1.0200x over previous
//
#include <hip/hip_runtime.h>
#include <hip/hip_bf16.h>

// Problem constants (from reference setup_inputs)
constexpr int NN   = 50000;   // nodes
constexpr int EE   = 400000;  // edges (before self loops)
constexpr int EP   = 450000;  // edges + self loops
constexpr int D    = 512;     // HEADS*CH
constexpr int D2   = 1024;    // XL||XR fused row stride
constexpr int F0   = 55;      // input feature dim
constexpr int F0P  = 64;      // padded to MFMA K granularity
constexpr int OUTC = 49;      // classifier out dim

typedef __hip_bfloat16 bf16;

using frag_ab  = __attribute__((ext_vector_type(8))) short;   // 8 bf16 (4 VGPRs)
using frag_cd4 = __attribute__((ext_vector_type(4))) float;   // 4 fp32 (16x16 acc)

__device__ inline void stf(float* p, float v) { *p = v; }
__device__ inline void stf(bf16* p, float v)  { *p = __float2bfloat16(v); }

// unpack 8 bf16 (packed in a uint4) to 8 floats
__device__ inline void unpack8(uint4 u, float* f) {
    unsigned w[4] = {u.x, u.y, u.z, u.w};
    #pragma unroll
    for (int j = 0; j < 4; ++j) {
        __hip_bfloat162 h = *(__hip_bfloat162*)&w[j];
        float2 t = __bfloat1622float2(h);
        f[2 * j] = t.x; f[2 * j + 1] = t.y;
    }
}

// ---------------------------------------------------------------------------
// Round-12: deep-phase MFMA GEMM (T2+T3+T4+T5), C[M,*] = A @ Bt^T.
// The 128x128/2-barrier structure pinned all pipes at ~20% (latency-bound;
// r11 counted-vmcnt graft was NULL per the T-catalog regime gate). This is
// the 8-phase-class structure adapted to thin K:
//   BM=256 BN=128 BK=64, 512 thr (8 waves, 4Mx2N), per-wave 64x64 out,
//   mfma_f32_16x16x32_bf16, acc[4][4].
//   3-slot LDS ring (A 32K + B 16K)x3 = 144 KB: compute s, s+1 resident,
//   stage s+2 (slot(s+2)==slot(s-1), reads done before boundary barrier).
//   Counted s_waitcnt vmcnt(6) at step boundaries only (6 loads/step/wave;
//   never 0 mid-loop). 2 phases/step: {ds_reads; 3 stage loads; barrier;
//   setprio(1); 16 MFMA; setprio(0); barrier}.
//   T2 swizzle per rule #21: LINEAR LDS dest (global_load_lds requirement),
//   inverse-permuted GLOBAL source chunk ch^(row&7), same XOR on ds_read.
// K = NS*64 compile-time (full unroll, static slot/frag indices).
// gridDim.x==8 -> XCD swizzle (A panel L2-resident per XCD).
// ---------------------------------------------------------------------------
template <typename TC, int NS>
__global__ __launch_bounds__(512) void gemm_8p(
    const bf16* __restrict__ A,   // [M,K]
    const bf16* __restrict__ Bt,  // [>=gridx*128 rows, K]
    TC* __restrict__ C,           // [M, Ncs]
    const float* __restrict__ bias,
    int M, int Ncs)
{
    constexpr int K  = NS * 64;
    constexpr int BM = 256, BN = 128, BK = 64;
    __shared__ __align__(16) bf16 As[3][BM * BK];   // 32 KB / slot
    __shared__ __align__(16) bf16 Bs[3][BN * BK];   // 16 KB / slot

    int bx = blockIdx.x, by = blockIdx.y;
    if (gridDim.x == 8) {
        int bid = by * 8 + bx;
        bx = (bid >> 3) & 7;
        by = (bid & 7) + ((bid >> 6) << 3);
    }
    if (by * BM >= M) return;   // uniform across block

    const int tid = threadIdx.x;
    const int w   = tid >> 6;       // wave 0..7
    const int l   = tid & 63;
    const int rowBase = by * BM;
    const int colBase = bx * BN;

    // ---- staging source pointers (inverse-swizzled global chunks) ----
    // chunk c = j*512 + tid; LDS row = c>>3, LDS chunk = c&7;
    // source chunk = (c&7) ^ (row&7)  [XOR involution, rule #21]
    const bf16* gA[4];
    #pragma unroll
    for (int j = 0; j < 4; ++j) {
        int c = j * 512 + tid;
        int row = c >> 3, chs = (c & 7) ^ (row & 7);
        int ar = rowBase + row; if (ar >= M) ar = M - 1;  // clamp, never stored
        gA[j] = A + (size_t)ar * K + chs * 8;
    }
    const bf16* gB[2];
    #pragma unroll
    for (int j = 0; j < 2; ++j) {
        int c = j * 512 + tid;
        int row = c >> 3, chs = (c & 7) ^ (row & 7);
        gB[j] = Bt + (size_t)(colBase + row) * K + chs * 8;   // Bt rows padded
    }

    // ---- fragment read offsets (swizzled), element units ----
    const int l15 = l & 15, l4 = l >> 4;
    const int wm = (w >> 1) * 64;   // wave M-block (4 x 64 rows)
    const int wn = (w & 1) * 64;    // wave N-block (2 x 64 cols)
    int aoff[4][2], boff[4][2];
    #pragma unroll
    for (int i = 0; i < 4; ++i) {
        int ra = wm + i * 16 + l15;
        int rb = wn + i * 16 + l15;
        #pragma unroll
        for (int ks = 0; ks < 2; ++ks) {
            aoff[i][ks] = ra * BK + (((ks * 4 + l4) ^ (ra & 7)) * 8);
            boff[i][ks] = rb * BK + (((ks * 4 + l4) ^ (rb & 7)) * 8);
        }
    }

    frag_cd4 acc[4][4] = {};

    // stage load p (0..5) of K-step s into ring slot s%3.
    // p 0..3 -> A chunks j=p; p 4..5 -> B chunks j=p-4.
    auto stage = [&](int s, int p) {
        int slot = s % 3;
        if (p < 4) {
            bf16* dst = &As[slot][(p * 512 + w * 64) * 8];   // wave-uniform base
            __builtin_amdgcn_global_load_lds(
                (const __attribute__((address_space(1))) void*)(gA[p] + s * BK),
                (__attribute__((address_space(3))) void*)dst, 16, 0, 0);
        } else {
            int j = p - 4;
            bf16* dst = &Bs[slot][(j * 512 + w * 64) * 8];
            __builtin_amdgcn_global_load_lds(
                (const __attribute__((address_space(1))) void*)(gB[j] + s * BK),
                (__attribute__((address_space(3))) void*)dst, 16, 0, 0);
        }
    };

    // ---- prologue: stage steps 0 and 1 (6 loads each) ----
    #pragma unroll
    for (int p = 0; p < 6; ++p) stage(0, p);
    if (NS > 1) {
        #pragma unroll
        for (int p = 0; p < 6; ++p) stage(1, p);
    }

    #pragma unroll
    for (int s = 0; s < NS; ++s) {
        // ---- step boundary: own step-s loads landed; s+1 stays in flight ----
        if (s + 1 < NS) asm volatile("s_waitcnt vmcnt(6)" ::: "memory");
        else            asm volatile("s_waitcnt vmcnt(0)" ::: "memory");
        __builtin_amdgcn_s_barrier();
        asm volatile("" ::: "memory");

        const bf16* Ab = As[s % 3];
        const bf16* Bb = Bs[s % 3];

        // ---- phase 1: all B frags + A frags mi=0,1; stage 3; MFMA 16 ----
        frag_ab bfr[4][2];
        #pragma unroll
        for (int ni = 0; ni < 4; ++ni)
            #pragma unroll
            for (int ks = 0; ks < 2; ++ks)
                bfr[ni][ks] = *(const frag_ab*)&Bb[boff[ni][ks]];
        frag_ab afr[2][2];
        #pragma unroll
        for (int mi = 0; mi < 2; ++mi)
            #pragma unroll
            for (int ks = 0; ks < 2; ++ks)
                afr[mi][ks] = *(const frag_ab*)&Ab[aoff[mi][ks]];
        if (s + 2 < NS) { stage(s + 2, 0); stage(s + 2, 1); stage(s + 2, 2); }

        __builtin_amdgcn_s_barrier();
        asm volatile("" ::: "memory");
        __builtin_amdgcn_s_setprio(1);
        #pragma unroll
        for (int mi = 0; mi < 2; ++mi)
            #pragma unroll
            for (int ni = 0; ni < 4; ++ni)
                #pragma unroll
                for (int ks = 0; ks < 2; ++ks)
                    acc[mi][ni] = __builtin_amdgcn_mfma_f32_16x16x32_bf16(
                        afr[mi][ks], bfr[ni][ks], acc[mi][ni], 0, 0, 0);
        __builtin_amdgcn_s_setprio(0);
        __builtin_amdgcn_s_barrier();
        asm volatile("" ::: "memory");

        // ---- phase 2: A frags mi=2,3; stage 3; MFMA 16 ----
        frag_ab afr2[2][2];
        #pragma unroll
        for (int mi = 0; mi < 2; ++mi)
            #pragma unroll
            for (int ks = 0; ks < 2; ++ks)
                afr2[mi][ks] = *(const frag_ab*)&Ab[aoff[mi + 2][ks]];
        if (s + 2 < NS) { stage(s + 2, 3); stage(s + 2, 4); stage(s + 2, 5); }

        __builtin_amdgcn_s_barrier();
        asm volatile("" ::: "memory");
        __builtin_amdgcn_s_setprio(1);
        #pragma unroll
        for (int mi = 0; mi < 2; ++mi)
            #pragma unroll
            for (int ni = 0; ni < 4; ++ni)
                #pragma unroll
                for (int ks = 0; ks < 2; ++ks)
                    acc[mi + 2][ni] = __builtin_amdgcn_mfma_f32_16x16x32_bf16(
                        afr2[mi][ks], bfr[ni][ks], acc[mi + 2][ni], 0, 0, 0);
        __builtin_amdgcn_s_setprio(0);
        // next boundary supplies vmcnt + barrier
    }

    // ---- epilogue: 16x16 C/D layout col=lane&15, row=(lane>>4)*4+reg ----
    // [m89/m91 verified; dtype-independent]
    #pragma unroll
    for (int mi = 0; mi < 4; ++mi) {
        #pragma unroll
        for (int r = 0; r < 4; ++r) {
            int row = rowBase + wm + mi * 16 + l4 * 4 + r;
            if (row >= M) continue;
            #pragma unroll
            for (int ni = 0; ni < 4; ++ni) {
                int col = colBase + wn + ni * 16 + l15;
                if (col >= Ncs) continue;
                float v = acc[mi][ni][r];
                if (bias) v += bias[col];
                stf(&C[(size_t)row * Ncs + col], v);
            }
        }
    }
}

// ---------------------------------------------------------------------------
// weight prep kernels
// ---------------------------------------------------------------------------
// fp32 W[512,512] x2 -> bf16 Wt[1024,512] (transposed, stacked), grid.z=2
__global__ void convert_transpose2(const float* __restrict__ W0,
                                   const float* __restrict__ W1,
                                   bf16* __restrict__ Wt) {
    __shared__ float tile[32][33];
    const float* W = blockIdx.z ? W1 : W0;
    bf16* dst = Wt + (size_t)blockIdx.z * D * D;
    int bn = blockIdx.x * 32, bk = blockIdx.y * 32;
    int tx = threadIdx.x & 31, ty = threadIdx.x >> 5;  // 32x8
    #pragma unroll
    for (int i = 0; i < 32; i += 8)
        tile[ty + i][tx] = W[(size_t)(bk + ty + i) * D + bn + tx];
    __syncthreads();
    #pragma unroll
    for (int i = 0; i < 32; i += 8)
        dst[(size_t)(bn + ty + i) * D + bk + tx] = __float2bfloat16(tile[tx][ty + i]);
}

__global__ void pad_convert_x(const float* __restrict__ x, bf16* __restrict__ Xp) {
    int idx = blockIdx.x * blockDim.x + threadIdx.x;
    if (idx >= NN * F0P) return;
    int n = idx >> 6, t = idx & 63;
    float v = (t < F0) ? x[n * F0 + t] : 0.f;
    Xp[idx] = __float2bfloat16(v);
}

// W1{l,r}[55,512] fp32 -> W1T[1024,64] bf16 (zero pad K), grid.y=2
__global__ void conv_transpose_w1(const float* __restrict__ Wl,
                                  const float* __restrict__ Wr,
                                  bf16* __restrict__ Wt) {
    const float* W = blockIdx.y ? Wr : Wl;
    bf16* dst = Wt + (size_t)blockIdx.y * D * F0P;
    int n = blockIdx.x;           // 512
    int k = threadIdx.x;          // 64
    float v = (k < F0) ? W[(size_t)k * D + n] : 0.f;
    dst[n * F0P + k] = __float2bfloat16(v);
}

__global__ void conv_transpose_wc(const float* __restrict__ W, bf16* __restrict__ Wt) {
    int n = blockIdx.x;           // 128
    for (int k = threadIdx.x; k < D; k += blockDim.x) {
        float v = (n < OUTC) ? W[(size_t)k * OUTC + n] : 0.f;
        Wt[(size_t)n * D + k] = __float2bfloat16(v);
    }
}

// ---------------------------------------------------------------------------
__global__ void zero_ints(int* __restrict__ p, int n) {
    int i = blockIdx.x * blockDim.x + threadIdx.x;
    if (i < n) p[i] = 0;
}

// ---------------------------------------------------------------------------
// CSR build by destination; srcPos[pos] = source node of CSR slot pos
// ---------------------------------------------------------------------------
__global__ void count_dst(const int* __restrict__ dstIdx, int* __restrict__ cnt) {
    int e = blockIdx.x * blockDim.x + threadIdx.x;
    if (e >= EP) return;
    int dst = (e < EE) ? dstIdx[e] : (e - EE);
    atomicAdd(&cnt[dst], 1);
}

__global__ void scan_blocks(const int* __restrict__ cnt, int* __restrict__ off,
                            int* __restrict__ bsum) {
    __shared__ int sh[1024];
    int i = blockIdx.x * 1024 + threadIdx.x;
    int v = (i < NN) ? cnt[i] : 0;
    sh[threadIdx.x] = v;
    __syncthreads();
    #pragma unroll
    for (int d = 1; d < 1024; d <<= 1) {
        int t = (threadIdx.x >= d) ? sh[threadIdx.x - d] : 0;
        __syncthreads();
        sh[threadIdx.x] += t;
        __syncthreads();
    }
    if (i < NN) off[i] = sh[threadIdx.x] - v;   // local exclusive
    if (threadIdx.x == 1023) bsum[blockIdx.x] = sh[1023];
}

__global__ void scan_bsums(int* __restrict__ bsum, int* __restrict__ bbase,
                           int* __restrict__ off, int nb) {
    int lane = threadIdx.x;  // single wave of 64
    int orig = (lane < nb) ? bsum[lane] : 0;
    int v = orig;
    #pragma unroll
    for (int d = 1; d < 64; d <<= 1) {
        int t = __shfl_up(v, d);
        if (lane >= d) v += t;
    }
    if (lane < nb) bbase[lane] = v - orig;      // exclusive base per block
    if (lane == 63) off[NN] = v;                // grand total
}

__global__ void add_base(int* __restrict__ off, const int* __restrict__ bbase) {
    int i = blockIdx.x * 1024 + threadIdx.x;
    if (blockIdx.x == 0 || i >= NN) return;
    off[i] += bbase[blockIdx.x];
}

__global__ void fill_srcpos(const int* __restrict__ srcIdx, const int* __restrict__ dstIdx,
                            const int* __restrict__ off, int* __restrict__ cnt,
                            int* __restrict__ srcPos) {
    int e = blockIdx.x * blockDim.x + threadIdx.x;
    if (e >= EP) return;
    int dst = (e < EE) ? dstIdx[e] : (e - EE);
    int src = (e < EE) ? srcIdx[e] : (e - EE);
    int pos = off[dst] + atomicAdd(&cnt[dst], 1);
    srcPos[pos] = src;
}

// ---------------------------------------------------------------------------
// FUSED per-node GATv2 edge phase — round-10 exact version (measured best).
// ONE wave per destination node, depth-2 prefetch, clamped-exp softmax.
// Lane l owns channels [l*8, l*8+8); head = l>>4.
// XLR row layout: [XL(512) | XR(512)] bf16, stride D2. Output Hb + bias + ELU.
// ---------------------------------------------------------------------------
__global__ __launch_bounds__(256) void gat_edge_fused(
    const bf16* __restrict__ XLR, const float* __restrict__ att,
    const int* __restrict__ off, const int* __restrict__ srcPos,
    const float* __restrict__ bias, bf16* __restrict__ Hout)
{
    int v = blockIdx.x * 4 + (threadIdx.x >> 6);
    if (v >= NN) return;
    int lane = threadIdx.x & 63;

    uint4 ru = *(const uint4*)(XLR + (size_t)v * D2 + D + lane * 8);
    float xr[8]; unpack8(ru, xr);
    const float4* a4 = (const float4*)(att + lane * 8);
    float4 aa = a4[0], ab = a4[1];
    float at[8] = {aa.x, aa.y, aa.z, aa.w, ab.x, ab.y, ab.z, ab.w};

    int s0 = off[v], s1 = off[v + 1];
    float den = 0.f;
    float acc[8] = {};

    uint4 lb0 = {0, 0, 0, 0}, lb1 = {0, 0, 0, 0};
    if (s0 < s1)     lb0 = *(const uint4*)(XLR + (size_t)srcPos[s0] * D2 + lane * 8);
    if (s0 + 1 < s1) lb1 = *(const uint4*)(XLR + (size_t)srcPos[s0 + 1] * D2 + lane * 8);

    for (int i = s0; i < s1; ++i) {
        uint4 cur = lb0;
        lb0 = lb1;
        if (i + 2 < s1)
            lb1 = *(const uint4*)(XLR + (size_t)srcPos[i + 2] * D2 + lane * 8);

        float xl[8]; unpack8(cur, xl);
        float sa = 0.f, sb = 0.f;
        #pragma unroll
        for (int j = 0; j < 4; ++j) {
            float t = xl[j] + xr[j];
            t = fmaxf(t, 0.2f * t);          // leaky relu (valid both signs)
            sa = fmaf(t, at[j], sa);
        }
        #pragma unroll
        for (int j = 4; j < 8; ++j) {
            float t = xl[j] + xr[j];
            t = fmaxf(t, 0.2f * t);
            sb = fmaf(t, at[j], sb);
        }
        float s = sa + sb;
        s += __shfl_xor(s, 1);
        s += __shfl_xor(s, 2);
        s += __shfl_xor(s, 4);
        s += __shfl_xor(s, 8);               // 16 lanes of head hold logit
        s = fminf(fmaxf(s, -60.f), 60.f);    // shift-free softmax, clamped
        float p = __expf(s);
        den += p;
        #pragma unroll
        for (int j = 0; j < 8; ++j) acc[j] = fmaf(p, xl[j], acc[j]);
    }
    float r = 1.f / den;

    const float4* b4 = (const float4*)(bias + lane * 8);
    float4 ba = b4[0], bb = b4[1];
    float bi[8] = {ba.x, ba.y, ba.z, ba.w, bb.x, bb.y, bb.z, bb.w};
    uint4 ou;
    unsigned* ow = (unsigned*)&ou;
    #pragma unroll
    for (int j = 0; j < 4; ++j) {
        float o0 = acc[2 * j] * r + bi[2 * j];
        float o1 = acc[2 * j + 1] * r + bi[2 * j + 1];
        o0 = o0 > 0.f ? o0 : (__expf(o0) - 1.f);   // ELU
        o1 = o1 > 0.f ? o1 : (__expf(o1) - 1.f);
        __hip_bfloat162 h{__float2bfloat16(o0), __float2bfloat16(o1)};
        ow[j] = *(unsigned*)&h;
    }
    *(uint4*)(Hout + (size_t)v * D + lane * 8) = ou;
}

// ---------------------------------------------------------------------------
extern "C" void kernel_launch(void* const* d_in, const int* in_sizes, int n_in,
                              void* d_out, int out_size, void* d_ws, size_t ws_size,
                              hipStream_t stream) {
    const float* x    = (const float*)d_in[0];
    const int*   ei   = (const int*)d_in[1];
    const float* W1l  = (const float*)d_in[2];
    const float* W1r  = (const float*)d_in[3];
    const float* att1 = (const float*)d_in[4];
    const float* b1   = (const float*)d_in[5];
    const float* W2l  = (const float*)d_in[6];
    const float* W2r  = (const float*)d_in[7];
    const float* att2 = (const float*)d_in[8];
    const float* b2   = (const float*)d_in[9];
    const float* Wc   = (const float*)d_in[10];
    const float* bc   = (const float*)d_in[11];
    float* out = (float*)d_out;

    const int* srcIdx = ei;
    const int* dstIdx = ei + EE;

    constexpr int NB = (NN + 1023) / 1024;   // 49 scan blocks

    // workspace carve — total ≈ 166 MB
    bf16* XLR  = (bf16*)d_ws;                    // NN*D2   (XL || XR)
    bf16* Hb   = XLR + (size_t)NN * D2;          // NN*D
    bf16* Xpad = Hb + (size_t)NN * D;            // NN*F0P
    bf16* W2T  = Xpad + (size_t)NN * F0P;        // 1024*D   (W2lT || W2rT rows)
    bf16* W1T  = W2T + (size_t)D2 * D;           // 1024*F0P
    bf16* WcT  = W1T + (size_t)D2 * F0P;         // 128*D
    int* cnt   = (int*)(WcT + (size_t)128 * D);  // NN
    int* cnt2  = cnt + NN;                       // NN
    int* off   = cnt2 + NN;                      // NN+1
    int* srcPos= off + (NN + 1);                 // EP
    int* bsum  = srcPos + EP;                    // NB
    int* bbase = bsum + NB;                      // NB

    // ---- one-time per call: CSR build + weight prep ----
    zero_ints<<<(2 * NN + 255) / 256, 256, 0, stream>>>(cnt, 2 * NN);
    count_dst<<<(EP + 255) / 256, 256, 0, stream>>>(dstIdx, cnt);
    scan_blocks<<<NB, 1024, 0, stream>>>(cnt, off, bsum);
    scan_bsums<<<1, 64, 0, stream>>>(bsum, bbase, off, NB);
    add_base<<<NB, 1024, 0, stream>>>(off, bbase);
    fill_srcpos<<<(EP + 255) / 256, 256, 0, stream>>>(srcIdx, dstIdx, off, cnt2, srcPos);

    dim3 ctGrid(D / 32, D / 32, 2);
    convert_transpose2<<<ctGrid, 256, 0, stream>>>(W2l, W2r, W2T);
    dim3 w1Grid(D, 2);
    conv_transpose_w1<<<w1Grid, F0P, 0, stream>>>(W1l, W1r, W1T);
    conv_transpose_wc<<<128, 256, 0, stream>>>(Wc, WcT);
    pad_convert_x<<<(NN * F0P + 255) / 256, 256, 0, stream>>>(x, Xpad);

    // BM=256 row-panels: pad grid.y so the XCD swizzle covers all panels
    int gy = (((NN + 255) / 256) + 7) / 8 * 8 + 8;      // 196 -> 208
    dim3 gemmGrid(D2 / 128, gy);                         // 8 x 208
    int nodeBlocks = (NN + 3) / 4;

    // ---- layer 1 (Xpad bf16, K=64): one GEMM produces XL||XR ----
    gemm_8p<bf16, 1><<<gemmGrid, 512, 0, stream>>>(Xpad, W1T, XLR, nullptr, NN, D2);
    gat_edge_fused<<<nodeBlocks, 256, 0, stream>>>(XLR, att1, off, srcPos, b1, Hb);

    // ---- layers 2 & 3 (bf16 Hb, K=512; conv2 applied twice) ----
    for (int rep = 0; rep < 2; ++rep) {
        gemm_8p<bf16, 8><<<gemmGrid, 512, 0, stream>>>(Hb, W2T, XLR, nullptr, NN, D2);
        gat_edge_fused<<<nodeBlocks, 256, 0, stream>>>(XLR, att2, off, srcPos, b2, Hb);
    }

    // ---- classifier: C[NN,49] fp32 = Hb @ Wc + bc (N padded to 128) ----
    dim3 gridc(1, (NN + 255) / 256);
    gemm_8p<float, 8><<<gridc, 512, 0, stream>>>(Hb, WcT, out, bc, NN, OUTC);
}

// Round 3
// 567.071 us; speedup vs baseline: 1.0906x; 1.0692x over previous
//
#include <hip/hip_runtime.h>
#include <hip/hip_bf16.h>

// Problem constants (from reference setup_inputs)
constexpr int NN   = 50000;   // nodes
constexpr int EE   = 400000;  // edges (before self loops)
constexpr int EP   = 450000;  // edges + self loops
constexpr int D    = 512;     // HEADS*CH
constexpr int D2   = 1024;    // XL||XR fused row stride
constexpr int F0   = 55;      // input feature dim
constexpr int F0P  = 64;      // padded to MFMA K granularity
constexpr int OUTC = 49;      // classifier out dim

typedef __hip_bfloat16 bf16;

using frag_ab  = __attribute__((ext_vector_type(8))) short;   // 8 bf16 (4 VGPRs)
using frag_cd4 = __attribute__((ext_vector_type(4))) float;   // 4 fp32 (16x16 acc)

__device__ inline void stf(float* p, float v) { *p = v; }
__device__ inline void stf(bf16* p, float v)  { *p = __float2bfloat16(v); }

// unpack 8 bf16 (packed in a uint4) to 8 floats
__device__ inline void unpack8(uint4 u, float* f) {
    unsigned w[4] = {u.x, u.y, u.z, u.w};
    #pragma unroll
    for (int j = 0; j < 4; ++j) {
        __hip_bfloat162 h = *(__hip_bfloat162*)&w[j];
        float2 t = __bfloat1622float2(h);
        f[2 * j] = t.x; f[2 * j + 1] = t.y;
    }
}

// ---------------------------------------------------------------------------
// Round-13: deep-pipeline GEMM, 2-blocks/CU variant. C[M,*] = A @ Bt^T.
// r12 (BK=64, 144 KB LDS, 1 blk/CU) verified T2 (bank conflicts 1.9e7->0)
// but stalled at MfmaUtil 23%: with ONE resident block the barrier schedule
// serializes LDS-read service (~1500 cyc/step/CU) against MFMA (~1240).
// Fix = restore cross-block pipe overlap (m114 mechanism):
//   BK=32, 3-slot ring (A 16K + B 8K)x3 = 72 KB  -> 2 blocks/CU,
//   __launch_bounds__(512,4) caps VGPR at 128 to guarantee residency.
//   Per K-step/wave: stage(s+2) 3x global_load_lds, 8x ds_read_b128,
//   16x mfma_16x16x32_bf16 (setprio-wrapped), ONE barrier, counted
//   s_waitcnt vmcnt(3) (step s landed; s+1 stays in flight; never 0
//   mid-loop). Mid-step barrier dropped: WAR on slot s-1 is ordered by
//   dep-chain (step s-1 ds_reads complete before its MFMAs issue, which
//   precede the boundary barrier that precedes stage(s+2)).
//   T2 swizzle (rule #21, both-sides): 4 chunks/row, chunk ^= (row>>1)&3
//   -> residual 2-way conflict (free, m136). Linear LDS dest
//   (global_load_lds requirement) + inverse-swizzled GLOBAL source +
//   same XOR on ds_read offsets.
// K = NS*32 compile-time (full unroll, static slot indices, rule #20).
// gridDim.x==8 -> XCD swizzle (A panel L2-resident per XCD).
// ---------------------------------------------------------------------------
template <typename TC, int NS>
__global__ __launch_bounds__(512, 4) void gemm_dp(
    const bf16* __restrict__ A,   // [M,K]
    const bf16* __restrict__ Bt,  // [>=gridx*128 rows, K]
    TC* __restrict__ C,           // [M, Ncs]
    const float* __restrict__ bias,
    int M, int Ncs)
{
    constexpr int K  = NS * 32;
    constexpr int BM = 256, BN = 128, BK = 32;
    __shared__ __align__(16) bf16 As[3][BM * BK];   // 16 KB / slot
    __shared__ __align__(16) bf16 Bs[3][BN * BK];   //  8 KB / slot

    int bx = blockIdx.x, by = blockIdx.y;
    if (gridDim.x == 8) {
        int bid = by * 8 + bx;
        bx = (bid >> 3) & 7;
        by = (bid & 7) + ((bid >> 6) << 3);
    }
    if (by * BM >= M) return;   // uniform across block

    const int tid = threadIdx.x;
    const int w   = tid >> 6;       // wave 0..7
    const int l   = tid & 63;
    const int rowBase = by * BM;
    const int colBase = bx * BN;

    // ---- staging source pointers (inverse-swizzled global chunks) ----
    // flat chunk f = j*512 + tid; LDS row = f>>2, LDS chunk = f&3;
    // source k-chunk = (f&3) ^ ((row>>1)&3)   [XOR involution, rule #21]
    const bf16* gA[2];
    #pragma unroll
    for (int j = 0; j < 2; ++j) {
        int f = j * 512 + tid;
        int row = f >> 2, c = (f & 3) ^ ((row >> 1) & 3);
        int ar = rowBase + row; if (ar >= M) ar = M - 1;  // clamp, never stored
        gA[j] = A + (size_t)ar * K + c * 8;
    }
    const bf16* gB;
    {
        int f = tid;
        int row = f >> 2, c = (f & 3) ^ ((row >> 1) & 3);
        gB = Bt + (size_t)(colBase + row) * K + c * 8;    // Bt rows padded
    }

    // ---- fragment read offsets (swizzled), element units ----
    const int l15 = l & 15, l4 = l >> 4;    // l4 = k-chunk 0..3
    const int wm = (w >> 1) * 64;   // wave M-block (4 x 64 rows)
    const int wn = (w & 1) * 64;    // wave N-block (2 x 64 cols)
    int aoff[4], boff[4];
    #pragma unroll
    for (int i = 0; i < 4; ++i) {
        int ra = wm + i * 16 + l15;
        int rb = wn + i * 16 + l15;
        aoff[i] = ra * BK + ((l4 ^ ((ra >> 1) & 3)) * 8);
        boff[i] = rb * BK + ((l4 ^ ((rb >> 1) & 3)) * 8);
    }

    frag_cd4 acc[4][4] = {};

    // stage K-step s into ring slot s%3 (3 x global_load_lds per wave)
    auto stage = [&](int s) {
        int slot = s % 3;
        __builtin_amdgcn_global_load_lds(
            (const __attribute__((address_space(1))) void*)(gA[0] + s * BK),
            (__attribute__((address_space(3))) void*)(&As[slot][(w * 64) * 8]),
            16, 0, 0);
        __builtin_amdgcn_global_load_lds(
            (const __attribute__((address_space(1))) void*)(gA[1] + s * BK),
            (__attribute__((address_space(3))) void*)(&As[slot][(512 + w * 64) * 8]),
            16, 0, 0);
        __builtin_amdgcn_global_load_lds(
            (const __attribute__((address_space(1))) void*)(gB + s * BK),
            (__attribute__((address_space(3))) void*)(&Bs[slot][(w * 64) * 8]),
            16, 0, 0);
    };

    // ---- prologue: stage steps 0 and 1 (3 loads each) ----
    stage(0);
    if (NS > 1) stage(1);

    #pragma unroll
    for (int s = 0; s < NS; ++s) {
        // boundary: own step-s loads landed; step s+1's stay in flight
        if (s + 1 < NS) asm volatile("s_waitcnt vmcnt(3)" ::: "memory");
        else            asm volatile("s_waitcnt vmcnt(0)" ::: "memory");
        __builtin_amdgcn_s_barrier();
        asm volatile("" ::: "memory");

        if (s + 2 < NS) stage(s + 2);   // overwrites slot(s-1): WAR-safe (see hdr)

        const bf16* Ab = As[s % 3];
        const bf16* Bb = Bs[s % 3];
        frag_ab a[4], b[4];
        #pragma unroll
        for (int i = 0; i < 4; ++i) a[i] = *(const frag_ab*)&Ab[aoff[i]];
        #pragma unroll
        for (int n = 0; n < 4; ++n) b[n] = *(const frag_ab*)&Bb[boff[n]];

        __builtin_amdgcn_s_setprio(1);
        #pragma unroll
        for (int i = 0; i < 4; ++i)
            #pragma unroll
            for (int n = 0; n < 4; ++n)
                acc[i][n] = __builtin_amdgcn_mfma_f32_16x16x32_bf16(
                    a[i], b[n], acc[i][n], 0, 0, 0);
        __builtin_amdgcn_s_setprio(0);
    }

    // ---- epilogue: 16x16 C/D layout col=lane&15, row=(lane>>4)*4+reg ----
    // [m89/m91 verified; dtype-independent]
    #pragma unroll
    for (int mi = 0; mi < 4; ++mi) {
        #pragma unroll
        for (int r = 0; r < 4; ++r) {
            int row = rowBase + wm + mi * 16 + l4 * 4 + r;
            if (row >= M) continue;
            #pragma unroll
            for (int ni = 0; ni < 4; ++ni) {
                int col = colBase + wn + ni * 16 + l15;
                if (col >= Ncs) continue;
                float v = acc[mi][ni][r];
                if (bias) v += bias[col];
                stf(&C[(size_t)row * Ncs + col], v);
            }
        }
    }
}

// ---------------------------------------------------------------------------
// weight prep kernels
// ---------------------------------------------------------------------------
// fp32 W[512,512] x2 -> bf16 Wt[1024,512] (transposed, stacked), grid.z=2
__global__ void convert_transpose2(const float* __restrict__ W0,
                                   const float* __restrict__ W1,
                                   bf16* __restrict__ Wt) {
    __shared__ float tile[32][33];
    const float* W = blockIdx.z ? W1 : W0;
    bf16* dst = Wt + (size_t)blockIdx.z * D * D;
    int bn = blockIdx.x * 32, bk = blockIdx.y * 32;
    int tx = threadIdx.x & 31, ty = threadIdx.x >> 5;  // 32x8
    #pragma unroll
    for (int i = 0; i < 32; i += 8)
        tile[ty + i][tx] = W[(size_t)(bk + ty + i) * D + bn + tx];
    __syncthreads();
    #pragma unroll
    for (int i = 0; i < 32; i += 8)
        dst[(size_t)(bn + ty + i) * D + bk + tx] = __float2bfloat16(tile[tx][ty + i]);
}

__global__ void pad_convert_x(const float* __restrict__ x, bf16* __restrict__ Xp) {
    int idx = blockIdx.x * blockDim.x + threadIdx.x;
    if (idx >= NN * F0P) return;
    int n = idx >> 6, t = idx & 63;
    float v = (t < F0) ? x[n * F0 + t] : 0.f;
    Xp[idx] = __float2bfloat16(v);
}

// W1{l,r}[55,512] fp32 -> W1T[1024,64] bf16 (zero pad K), grid.y=2
__global__ void conv_transpose_w1(const float* __restrict__ Wl,
                                  const float* __restrict__ Wr,
                                  bf16* __restrict__ Wt) {
    const float* W = blockIdx.y ? Wr : Wl;
    bf16* dst = Wt + (size_t)blockIdx.y * D * F0P;
    int n = blockIdx.x;           // 512
    int k = threadIdx.x;          // 64
    float v = (k < F0) ? W[(size_t)k * D + n] : 0.f;
    dst[n * F0P + k] = __float2bfloat16(v);
}

__global__ void conv_transpose_wc(const float* __restrict__ W, bf16* __restrict__ Wt) {
    int n = blockIdx.x;           // 128
    for (int k = threadIdx.x; k < D; k += blockDim.x) {
        float v = (n < OUTC) ? W[(size_t)k * OUTC + n] : 0.f;
        Wt[(size_t)n * D + k] = __float2bfloat16(v);
    }
}

// ---------------------------------------------------------------------------
__global__ void zero_ints(int* __restrict__ p, int n) {
    int i = blockIdx.x * blockDim.x + threadIdx.x;
    if (i < n) p[i] = 0;
}

// ---------------------------------------------------------------------------
// CSR build by destination; srcPos[pos] = source node of CSR slot pos
// ---------------------------------------------------------------------------
__global__ void count_dst(const int* __restrict__ dstIdx, int* __restrict__ cnt) {
    int e = blockIdx.x * blockDim.x + threadIdx.x;
    if (e >= EP) return;
    int dst = (e < EE) ? dstIdx[e] : (e - EE);
    atomicAdd(&cnt[dst], 1);
}

__global__ void scan_blocks(const int* __restrict__ cnt, int* __restrict__ off,
                            int* __restrict__ bsum) {
    __shared__ int sh[1024];
    int i = blockIdx.x * 1024 + threadIdx.x;
    int v = (i < NN) ? cnt[i] : 0;
    sh[threadIdx.x] = v;
    __syncthreads();
    #pragma unroll
    for (int d = 1; d < 1024; d <<= 1) {
        int t = (threadIdx.x >= d) ? sh[threadIdx.x - d] : 0;
        __syncthreads();
        sh[threadIdx.x] += t;
        __syncthreads();
    }
    if (i < NN) off[i] = sh[threadIdx.x] - v;   // local exclusive
    if (threadIdx.x == 1023) bsum[blockIdx.x] = sh[1023];
}

__global__ void scan_bsums(int* __restrict__ bsum, int* __restrict__ bbase,
                           int* __restrict__ off, int nb) {
    int lane = threadIdx.x;  // single wave of 64
    int orig = (lane < nb) ? bsum[lane] : 0;
    int v = orig;
    #pragma unroll
    for (int d = 1; d < 64; d <<= 1) {
        int t = __shfl_up(v, d);
        if (lane >= d) v += t;
    }
    if (lane < nb) bbase[lane] = v - orig;      // exclusive base per block
    if (lane == 63) off[NN] = v;                // grand total
}

__global__ void add_base(int* __restrict__ off, const int* __restrict__ bbase) {
    int i = blockIdx.x * 1024 + threadIdx.x;
    if (blockIdx.x == 0 || i >= NN) return;
    off[i] += bbase[blockIdx.x];
}

__global__ void fill_srcpos(const int* __restrict__ srcIdx, const int* __restrict__ dstIdx,
                            const int* __restrict__ off, int* __restrict__ cnt,
                            int* __restrict__ srcPos) {
    int e = blockIdx.x * blockDim.x + threadIdx.x;
    if (e >= EP) return;
    int dst = (e < EE) ? dstIdx[e] : (e - EE);
    int src = (e < EE) ? srcIdx[e] : (e - EE);
    int pos = off[dst] + atomicAdd(&cnt[dst], 1);
    srcPos[pos] = src;
}

// ---------------------------------------------------------------------------
// FUSED per-node GATv2 edge phase — round-10 exact version (measured best).
// ONE wave per destination node, depth-2 prefetch, clamped-exp softmax.
// Lane l owns channels [l*8, l*8+8); head = l>>4.
// XLR row layout: [XL(512) | XR(512)] bf16, stride D2. Output Hb + bias + ELU.
// ---------------------------------------------------------------------------
__global__ __launch_bounds__(256) void gat_edge_fused(
    const bf16* __restrict__ XLR, const float* __restrict__ att,
    const int* __restrict__ off, const int* __restrict__ srcPos,
    const float* __restrict__ bias, bf16* __restrict__ Hout)
{
    int v = blockIdx.x * 4 + (threadIdx.x >> 6);
    if (v >= NN) return;
    int lane = threadIdx.x & 63;

    uint4 ru = *(const uint4*)(XLR + (size_t)v * D2 + D + lane * 8);
    float xr[8]; unpack8(ru, xr);
    const float4* a4 = (const float4*)(att + lane * 8);
    float4 aa = a4[0], ab = a4[1];
    float at[8] = {aa.x, aa.y, aa.z, aa.w, ab.x, ab.y, ab.z, ab.w};

    int s0 = off[v], s1 = off[v + 1];
    float den = 0.f;
    float acc[8] = {};

    uint4 lb0 = {0, 0, 0, 0}, lb1 = {0, 0, 0, 0};
    if (s0 < s1)     lb0 = *(const uint4*)(XLR + (size_t)srcPos[s0] * D2 + lane * 8);
    if (s0 + 1 < s1) lb1 = *(const uint4*)(XLR + (size_t)srcPos[s0 + 1] * D2 + lane * 8);

    for (int i = s0; i < s1; ++i) {
        uint4 cur = lb0;
        lb0 = lb1;
        if (i + 2 < s1)
            lb1 = *(const uint4*)(XLR + (size_t)srcPos[i + 2] * D2 + lane * 8);

        float xl[8]; unpack8(cur, xl);
        float sa = 0.f, sb = 0.f;
        #pragma unroll
        for (int j = 0; j < 4; ++j) {
            float t = xl[j] + xr[j];
            t = fmaxf(t, 0.2f * t);          // leaky relu (valid both signs)
            sa = fmaf(t, at[j], sa);
        }
        #pragma unroll
        for (int j = 4; j < 8; ++j) {
            float t = xl[j] + xr[j];
            t = fmaxf(t, 0.2f * t);
            sb = fmaf(t, at[j], sb);
        }
        float s = sa + sb;
        s += __shfl_xor(s, 1);
        s += __shfl_xor(s, 2);
        s += __shfl_xor(s, 4);
        s += __shfl_xor(s, 8);               // 16 lanes of head hold logit
        s = fminf(fmaxf(s, -60.f), 60.f);    // shift-free softmax, clamped
        float p = __expf(s);
        den += p;
        #pragma unroll
        for (int j = 0; j < 8; ++j) acc[j] = fmaf(p, xl[j], acc[j]);
    }
    float r = 1.f / den;

    const float4* b4 = (const float4*)(bias + lane * 8);
    float4 ba = b4[0], bb = b4[1];
    float bi[8] = {ba.x, ba.y, ba.z, ba.w, bb.x, bb.y, bb.z, bb.w};
    uint4 ou;
    unsigned* ow = (unsigned*)&ou;
    #pragma unroll
    for (int j = 0; j < 4; ++j) {
        float o0 = acc[2 * j] * r + bi[2 * j];
        float o1 = acc[2 * j + 1] * r + bi[2 * j + 1];
        o0 = o0 > 0.f ? o0 : (__expf(o0) - 1.f);   // ELU
        o1 = o1 > 0.f ? o1 : (__expf(o1) - 1.f);
        __hip_bfloat162 h{__float2bfloat16(o0), __float2bfloat16(o1)};
        ow[j] = *(unsigned*)&h;
    }
    *(uint4*)(Hout + (size_t)v * D + lane * 8) = ou;
}

// ---------------------------------------------------------------------------
extern "C" void kernel_launch(void* const* d_in, const int* in_sizes, int n_in,
                              void* d_out, int out_size, void* d_ws, size_t ws_size,
                              hipStream_t stream) {
    const float* x    = (const float*)d_in[0];
    const int*   ei   = (const int*)d_in[1];
    const float* W1l  = (const float*)d_in[2];
    const float* W1r  = (const float*)d_in[3];
    const float* att1 = (const float*)d_in[4];
    const float* b1   = (const float*)d_in[5];
    const float* W2l  = (const float*)d_in[6];
    const float* W2r  = (const float*)d_in[7];
    const float* att2 = (const float*)d_in[8];
    const float* b2   = (const float*)d_in[9];
    const float* Wc   = (const float*)d_in[10];
    const float* bc   = (const float*)d_in[11];
    float* out = (float*)d_out;

    const int* srcIdx = ei;
    const int* dstIdx = ei + EE;

    constexpr int NB = (NN + 1023) / 1024;   // 49 scan blocks

    // workspace carve — total ≈ 166 MB
    bf16* XLR  = (bf16*)d_ws;                    // NN*D2   (XL || XR)
    bf16* Hb   = XLR + (size_t)NN * D2;          // NN*D
    bf16* Xpad = Hb + (size_t)NN * D;            // NN*F0P
    bf16* W2T  = Xpad + (size_t)NN * F0P;        // 1024*D   (W2lT || W2rT rows)
    bf16* W1T  = W2T + (size_t)D2 * D;           // 1024*F0P
    bf16* WcT  = W1T + (size_t)D2 * F0P;         // 128*D
    int* cnt   = (int*)(WcT + (size_t)128 * D);  // NN
    int* cnt2  = cnt + NN;                       // NN
    int* off   = cnt2 + NN;                      // NN+1
    int* srcPos= off + (NN + 1);                 // EP
    int* bsum  = srcPos + EP;                    // NB
    int* bbase = bsum + NB;                      // NB

    // ---- one-time per call: CSR build + weight prep ----
    zero_ints<<<(2 * NN + 255) / 256, 256, 0, stream>>>(cnt, 2 * NN);
    count_dst<<<(EP + 255) / 256, 256, 0, stream>>>(dstIdx, cnt);
    scan_blocks<<<NB, 1024, 0, stream>>>(cnt, off, bsum);
    scan_bsums<<<1, 64, 0, stream>>>(bsum, bbase, off, NB);
    add_base<<<NB, 1024, 0, stream>>>(off, bbase);
    fill_srcpos<<<(EP + 255) / 256, 256, 0, stream>>>(srcIdx, dstIdx, off, cnt2, srcPos);

    dim3 ctGrid(D / 32, D / 32, 2);
    convert_transpose2<<<ctGrid, 256, 0, stream>>>(W2l, W2r, W2T);
    dim3 w1Grid(D, 2);
    conv_transpose_w1<<<w1Grid, F0P, 0, stream>>>(W1l, W1r, W1T);
    conv_transpose_wc<<<128, 256, 0, stream>>>(Wc, WcT);
    pad_convert_x<<<(NN * F0P + 255) / 256, 256, 0, stream>>>(x, Xpad);

    // BM=256 row-panels: pad grid.y to a multiple of 8 for the XCD swizzle
    int panels = (NN + 255) / 256;                       // 196
    int gy = (panels + 7) / 8 * 8;                       // 200
    dim3 gemmGrid(D2 / 128, gy);                         // 8 x 200
    int nodeBlocks = (NN + 3) / 4;

    // ---- layer 1 (Xpad bf16, K=64): one GEMM produces XL||XR ----
    gemm_dp<bf16, 2><<<gemmGrid, 512, 0, stream>>>(Xpad, W1T, XLR, nullptr, NN, D2);
    gat_edge_fused<<<nodeBlocks, 256, 0, stream>>>(XLR, att1, off, srcPos, b1, Hb);

    // ---- layers 2 & 3 (bf16 Hb, K=512; conv2 applied twice) ----
    for (int rep = 0; rep < 2; ++rep) {
        gemm_dp<bf16, 16><<<gemmGrid, 512, 0, stream>>>(Hb, W2T, XLR, nullptr, NN, D2);
        gat_edge_fused<<<nodeBlocks, 256, 0, stream>>>(XLR, att2, off, srcPos, b2, Hb);
    }

    // ---- classifier: C[NN,49] fp32 = Hb @ Wc + bc (N padded to 128) ----
    dim3 gridc(1, panels);
    gemm_dp<float, 16><<<gridc, 512, 0, stream>>>(Hb, WcT, out, bc, NN, OUTC);
}